// Round 1
// baseline (529.744 us; speedup 1.0000x reference)
//
#include <hip/hip_runtime.h>

#define LN_EPS 1e-5f

constexpr int ROWS_PER_BLOCK = 32;
constexpr int ROWS_PER_WAVE  = 8;    // 4 waves * 8 rows = 32
constexpr int KDIM = 192;
constexpr int NOUT = 256;

__global__ __launch_bounds__(256)
void user_tower_kernel(const int*   __restrict__ user_input,
                       const float* __restrict__ emb,
                       const int*   __restrict__ sc_country_idx,
                       const float* __restrict__ sc_country_emb,
                       const int*   __restrict__ sc_device_idx,
                       const float* __restrict__ sc_device_emb,
                       const int*   __restrict__ mf_tags_idx,
                       const float* __restrict__ mf_tags_emb,
                       const int*   __restrict__ mf_history_idx,
                       const float* __restrict__ mf_history_emb,
                       const float* __restrict__ fc_w,
                       const float* __restrict__ fc_b,
                       const float* __restrict__ ln_g,
                       const float* __restrict__ ln_b,
                       float*       __restrict__ out,
                       int B)
{
    __shared__ float X[ROWS_PER_BLOCK][KDIM];   // 24 KB

    const int tid  = threadIdx.x;
    const int lane = tid & 63;
    const int wave = tid >> 6;
    const int row0 = blockIdx.x * ROWS_PER_BLOCK;

    const int half = lane >> 5;   // 0 or 1
    const int col  = lane & 31;   // 0..31

    // ---------------- Phase 1: gather 8 rows per wave into LDS ----------------
    for (int i = 0; i < ROWS_PER_WAVE; ++i) {
        const int r   = wave * ROWS_PER_WAVE + i;
        const int row = row0 + r;
        if (row < B) {
            const int u = __builtin_amdgcn_readfirstlane(user_input[row]);

            // main embedding: 64 floats, one per lane (coalesced 256B)
            X[r][lane] = emb[u * 64 + lane];

            // scalar side features: country (lanes 0-31), device (lanes 32-63)
            if (half == 0) {
                const int ci = sc_country_idx[u];
                X[r][64 + col] = sc_country_emb[ci * 32 + col];
            } else {
                const int di = sc_device_idx[u];
                X[r][96 + col] = sc_device_emb[di * 32 + col];
            }

            // tags mean-pool (W=20): 2 pooled rows per wave-iteration
            {
                float a = 0.f;
                const int* __restrict__ ip = mf_tags_idx + u * 20;
                #pragma unroll
                for (int j = 0; j < 20; j += 2) {
                    const int idx = ip[j + half];
                    a += mf_tags_emb[idx * 32 + col];
                }
                a += __shfl_xor(a, 32, 64);
                if (half == 0) X[r][128 + col] = a * (1.f / 20.f);
            }

            // history mean-pool (W=50)
            {
                float a = 0.f;
                const int* __restrict__ ip = mf_history_idx + u * 50;
                #pragma unroll
                for (int j = 0; j < 50; j += 2) {
                    const int idx = ip[j + half];
                    a += mf_history_emb[idx * 32 + col];
                }
                a += __shfl_xor(a, 32, 64);
                if (half == 0) X[r][160 + col] = a * (1.f / 50.f);
            }
        }
    }
    __syncthreads();

    // ---------------- Phase 2: FC 192 -> 256 (8 rows x 4 cols per thread) ----------------
    // wave handles rows [wave*8, wave*8+8); lane handles cols {lane + 64*ci}
    const int c0 = lane;
    float acc[ROWS_PER_WAVE][4];
    float g4[4], b4[4];
    #pragma unroll
    for (int ci = 0; ci < 4; ++ci) {
        const int c = c0 + 64 * ci;
        const float bias = fc_b[c];
        g4[ci] = ln_g[c];
        b4[ci] = ln_b[c];
        #pragma unroll
        for (int ri = 0; ri < ROWS_PER_WAVE; ++ri) acc[ri][ci] = bias;
    }

    for (int kc = 0; kc < KDIM; kc += 4) {
        float4 w[4];
        #pragma unroll
        for (int ci = 0; ci < 4; ++ci)
            w[ci] = *(const float4*)&fc_w[(c0 + 64 * ci) * KDIM + kc];
        #pragma unroll
        for (int ri = 0; ri < ROWS_PER_WAVE; ++ri) {
            const float4 x = *(const float4*)&X[wave * ROWS_PER_WAVE + ri][kc];
            #pragma unroll
            for (int ci = 0; ci < 4; ++ci) {
                acc[ri][ci] += x.x * w[ci].x + x.y * w[ci].y
                             + x.z * w[ci].z + x.w * w[ci].w;
            }
        }
    }

    // ---------------- Phase 3: ReLU + LayerNorm (wave-local) + store ----------------
    #pragma unroll
    for (int ri = 0; ri < ROWS_PER_WAVE; ++ri) {
        const int row = row0 + wave * ROWS_PER_WAVE + ri;
        float y[4];
        float s = 0.f, s2 = 0.f;
        #pragma unroll
        for (int ci = 0; ci < 4; ++ci) {
            y[ci] = fmaxf(acc[ri][ci], 0.f);
            s  += y[ci];
            s2 += y[ci] * y[ci];
        }
        #pragma unroll
        for (int m = 32; m >= 1; m >>= 1) {
            s  += __shfl_xor(s,  m, 64);
            s2 += __shfl_xor(s2, m, 64);
        }
        const float mu  = s  * (1.f / 256.f);
        const float var = s2 * (1.f / 256.f) - mu * mu;
        const float rs  = rsqrtf(var + LN_EPS);
        if (row < B) {
            #pragma unroll
            for (int ci = 0; ci < 4; ++ci) {
                const int c = c0 + 64 * ci;
                out[row * NOUT + c] = (y[ci] - mu) * rs * g4[ci] + b4[ci];
            }
        }
    }
}

extern "C" void kernel_launch(void* const* d_in, const int* in_sizes, int n_in,
                              void* d_out, int out_size, void* d_ws, size_t ws_size,
                              hipStream_t stream)
{
    const int*   user_input     = (const int*)  d_in[0];
    const float* emb            = (const float*)d_in[1];
    const int*   sc_country_idx = (const int*)  d_in[2];
    const float* sc_country_emb = (const float*)d_in[3];
    const int*   sc_device_idx  = (const int*)  d_in[4];
    const float* sc_device_emb  = (const float*)d_in[5];
    const int*   mf_tags_idx    = (const int*)  d_in[6];
    const float* mf_tags_emb    = (const float*)d_in[7];
    const int*   mf_history_idx = (const int*)  d_in[8];
    const float* mf_history_emb = (const float*)d_in[9];
    const float* fc_w           = (const float*)d_in[10];
    const float* fc_b           = (const float*)d_in[11];
    const float* ln_g           = (const float*)d_in[12];
    const float* ln_b           = (const float*)d_in[13];
    float*       out            = (float*)d_out;

    const int B = in_sizes[0];
    const int grid = (B + ROWS_PER_BLOCK - 1) / ROWS_PER_BLOCK;

    user_tower_kernel<<<grid, 256, 0, stream>>>(
        user_input, emb, sc_country_idx, sc_country_emb,
        sc_device_idx, sc_device_emb, mf_tags_idx, mf_tags_emb,
        mf_history_idx, mf_history_emb, fc_w, fc_b, ln_g, ln_b, out, B);
}

// Round 2
// 516.499 us; speedup vs baseline: 1.0256x; 1.0256x over previous
//
#include <hip/hip_runtime.h>

#define LN_EPS 1e-5f

constexpr int KDIM = 192;
constexpr int NOUT = 256;
constexpr int ROWS_PER_BLOCK = 32;   // FC kernel tile
constexpr int ROWS_PER_WAVE  = 8;

// ---------------------------------------------------------------------------
// Kernel A: gather + pool.  One wave per output row -> 16384 waves in flight.
// Writes X[B][192] to workspace.
// ---------------------------------------------------------------------------
__global__ __launch_bounds__(256)
void ut_gather_kernel(const int*   __restrict__ user_input,
                      const float* __restrict__ emb,
                      const int*   __restrict__ sc_country_idx,
                      const float* __restrict__ sc_country_emb,
                      const int*   __restrict__ sc_device_idx,
                      const float* __restrict__ sc_device_emb,
                      const int*   __restrict__ mf_tags_idx,
                      const float* __restrict__ mf_tags_emb,
                      const int*   __restrict__ mf_history_idx,
                      const float* __restrict__ mf_history_emb,
                      float*       __restrict__ X,
                      int B)
{
    const int lane = threadIdx.x & 63;
    const int wave = threadIdx.x >> 6;
    const int row  = blockIdx.x * 4 + wave;
    if (row >= B) return;                       // wave-uniform exit

    const int half = lane >> 5;                 // 0 or 1
    const int col  = lane & 31;                 // 0..31

    const int u = __builtin_amdgcn_readfirstlane(user_input[row]);
    float* __restrict__ Xr = X + (size_t)row * KDIM;

    // ---- issue all index loads first (independent) ----
    const int ci = sc_country_idx[u];
    const int di = sc_device_idx[u];

    const int* __restrict__ tp = mf_tags_idx    + (size_t)u * 20;
    const int* __restrict__ hp = mf_history_idx + (size_t)u * 50;
    int tix[10];
    #pragma unroll
    for (int j = 0; j < 10; ++j) tix[j] = tp[2 * j + half];
    int hix[25];
    #pragma unroll
    for (int j = 0; j < 25; ++j) hix[j] = hp[2 * j + half];

    // ---- main embedding: 64 floats, one per lane ----
    const float e = emb[(size_t)u * 64 + lane];

    // ---- side features ----
    const float sc = (half == 0) ? sc_country_emb[ci * 32 + col]
                                 : sc_device_emb [di * 32 + col];

    // ---- pooled gathers (all independent) ----
    float ta = 0.f;
    #pragma unroll
    for (int j = 0; j < 10; ++j) ta += mf_tags_emb[tix[j] * 32 + col];
    float ha = 0.f;
    #pragma unroll
    for (int j = 0; j < 25; ++j) ha += mf_history_emb[hix[j] * 32 + col];

    ta += __shfl_xor(ta, 32, 64);
    ha += __shfl_xor(ha, 32, 64);

    // ---- write the 192-float row ----
    Xr[lane] = e;                                   // cols 0..63
    if (half == 0) {
        Xr[64  + col] = sc;                         // country: 64..95
        Xr[128 + col] = ta * (1.f / 20.f);          // tags:    128..159
        Xr[160 + col] = ha * (1.f / 50.f);          // history: 160..191
    } else {
        Xr[96  + col] = sc;                         // device:  96..127
    }
}

// ---------------------------------------------------------------------------
// Kernel B: FC 192->256 + ReLU + LayerNorm.  32 rows per block, 8 per wave.
// ---------------------------------------------------------------------------
__global__ __launch_bounds__(256)
void ut_fc_ln_kernel(const float* __restrict__ Xg,
                     const float* __restrict__ fc_w,
                     const float* __restrict__ fc_b,
                     const float* __restrict__ ln_g,
                     const float* __restrict__ ln_b,
                     float*       __restrict__ out,
                     int B)
{
    __shared__ float X[ROWS_PER_BLOCK][KDIM];   // 24 KB

    const int tid  = threadIdx.x;
    const int lane = tid & 63;
    const int wave = tid >> 6;
    const int row0 = blockIdx.x * ROWS_PER_BLOCK;

    // ---- stage X tile: 32*192 floats = 1536 float4, 6 per thread ----
    {
        const float4* __restrict__ src = (const float4*)(Xg + (size_t)row0 * KDIM);
        float4* dst = (float4*)&X[0][0];
        #pragma unroll
        for (int i = 0; i < 6; ++i) dst[tid + 256 * i] = src[tid + 256 * i];
    }
    __syncthreads();

    // ---- FC: wave handles rows [wave*8, wave*8+8), lane handles cols lane+64*ci ----
    const int c0 = lane;
    float acc[ROWS_PER_WAVE][4];
    float g4[4], b4[4];
    #pragma unroll
    for (int ci = 0; ci < 4; ++ci) {
        const int c = c0 + 64 * ci;
        const float bias = fc_b[c];
        g4[ci] = ln_g[c];
        b4[ci] = ln_b[c];
        #pragma unroll
        for (int ri = 0; ri < ROWS_PER_WAVE; ++ri) acc[ri][ci] = bias;
    }

    for (int kc = 0; kc < KDIM; kc += 4) {
        float4 w[4];
        #pragma unroll
        for (int ci = 0; ci < 4; ++ci)
            w[ci] = *(const float4*)&fc_w[(c0 + 64 * ci) * KDIM + kc];
        #pragma unroll
        for (int ri = 0; ri < ROWS_PER_WAVE; ++ri) {
            const float4 x = *(const float4*)&X[wave * ROWS_PER_WAVE + ri][kc];
            #pragma unroll
            for (int ci = 0; ci < 4; ++ci) {
                acc[ri][ci] += x.x * w[ci].x + x.y * w[ci].y
                             + x.z * w[ci].z + x.w * w[ci].w;
            }
        }
    }

    // ---- ReLU + LayerNorm (wave-local rows) + store ----
    #pragma unroll
    for (int ri = 0; ri < ROWS_PER_WAVE; ++ri) {
        const int row = row0 + wave * ROWS_PER_WAVE + ri;
        float y[4];
        float s = 0.f, s2 = 0.f;
        #pragma unroll
        for (int ci = 0; ci < 4; ++ci) {
            y[ci] = fmaxf(acc[ri][ci], 0.f);
            s  += y[ci];
            s2 += y[ci] * y[ci];
        }
        #pragma unroll
        for (int m = 32; m >= 1; m >>= 1) {
            s  += __shfl_xor(s,  m, 64);
            s2 += __shfl_xor(s2, m, 64);
        }
        const float mu  = s  * (1.f / 256.f);
        const float var = s2 * (1.f / 256.f) - mu * mu;
        const float rs  = rsqrtf(var + LN_EPS);
        if (row < B) {
            #pragma unroll
            for (int ci = 0; ci < 4; ++ci) {
                const int c = c0 + 64 * ci;
                out[row * NOUT + c] = (y[ci] - mu) * rs * g4[ci] + b4[ci];
            }
        }
    }
}

extern "C" void kernel_launch(void* const* d_in, const int* in_sizes, int n_in,
                              void* d_out, int out_size, void* d_ws, size_t ws_size,
                              hipStream_t stream)
{
    const int*   user_input     = (const int*)  d_in[0];
    const float* emb            = (const float*)d_in[1];
    const int*   sc_country_idx = (const int*)  d_in[2];
    const float* sc_country_emb = (const float*)d_in[3];
    const int*   sc_device_idx  = (const int*)  d_in[4];
    const float* sc_device_emb  = (const float*)d_in[5];
    const int*   mf_tags_idx    = (const int*)  d_in[6];
    const float* mf_tags_emb    = (const float*)d_in[7];
    const int*   mf_history_idx = (const int*)  d_in[8];
    const float* mf_history_emb = (const float*)d_in[9];
    const float* fc_w           = (const float*)d_in[10];
    const float* fc_b           = (const float*)d_in[11];
    const float* ln_g           = (const float*)d_in[12];
    const float* ln_b           = (const float*)d_in[13];
    float*       out            = (float*)d_out;
    float*       X              = (float*)d_ws;     // [B][192], 12.6 MB

    const int B = in_sizes[0];

    const int gatherGrid = (B + 3) / 4;             // 4 rows (waves) per block
    ut_gather_kernel<<<gatherGrid, 256, 0, stream>>>(
        user_input, emb, sc_country_idx, sc_country_emb,
        sc_device_idx, sc_device_emb, mf_tags_idx, mf_tags_emb,
        mf_history_idx, mf_history_emb, X, B);

    const int fcGrid = (B + ROWS_PER_BLOCK - 1) / ROWS_PER_BLOCK;
    ut_fc_ln_kernel<<<fcGrid, 256, 0, stream>>>(
        X, fc_w, fc_b, ln_g, ln_b, out, B);
}